// Round 10
// baseline (32.404 us; speedup 1.0000x reference)
//
#include <hip/hip_runtime.h>

#define N_NODES 8192
#define T_TYPES 8
#define HIN 256     // H*IN
#define OUTF 64
#define G3 192      // 3*OUT
#define BM 64       // nodes per fused block
#define MAXBLK 135  // 8192/64 + up to 7 partial chunks

typedef __attribute__((ext_vector_type(8))) __bf16 bf16x8;
typedef __attribute__((ext_vector_type(4))) float f32x4;

// workspace byte offsets
#define WS_CURS 0
#define WS_PERM 256
#define WS_WAT  (256 + 262144)           // 8 types * 32768 B (bf16 [64][256], pre-swizzled)
#define WS_WIT  (WS_WAT + 262144)        // 8 types * 24576 B (bf16 [192][64], pre-swizzled)
#define WS_WHT  (WS_WIT + 196608)        // 8 types * 24576 B

// LDS byte offsets (fused kernel, BM=64)
#define L_XS  0        // X [64][256] bf16, swizzled          32768
#define L_WAS 32768    // WaT [64][256] bf16, swizzled        32768
#define L_WIS 65536    // WiT [192][64] bf16, swizzled        24576
#define L_WHS 90112    // WhT [192][64] bf16, swizzled        24576
#define L_YS  114688   // Y [64][64] bf16, swizzled            8192
#define L_HS  122880   // H [64][64] bf16, swizzled            8192
#define L_IDX 131072   // 64 ints                               256
#define L_TOT 131328

#define GLD_LDS16(g, l) __builtin_amdgcn_global_load_lds( \
    (const __attribute__((address_space(1))) void*)(g),   \
    (__attribute__((address_space(3))) void*)(l), 16, 0, 0)

__device__ __forceinline__ unsigned short f2bf(float f) {
    unsigned u = __float_as_uint(f);
    return (unsigned short)((u + 0x7FFFu + ((u >> 16) & 1u)) >> 16);
}
__device__ __forceinline__ int pack2bf(float a, float b) {
    return (int)f2bf(a) | ((int)f2bf(b) << 16);
}

// K1: blocks 0-79 = parallel weight transpose/bf16/pre-swizzle (1 tile each);
//     blocks 80-111 = parallel windowed scatter (full in-block scan, each block
//     writes only the perm entries owned by its 8 threads; zero global atomics).
__global__ __launch_bounds__(256) void prep_and_scatter(
    const float* __restrict__ W_att, const float* __restrict__ W_in,
    const float* __restrict__ W_hid, const int* __restrict__ nt,
    int* __restrict__ cursors, int* __restrict__ perm,
    unsigned short* __restrict__ waT, unsigned short* __restrict__ wiT,
    unsigned short* __restrict__ whT)
{
    __shared__ float Lf[64][68];                      // prep path (17.4 KB)
    __shared__ unsigned long long scA[256], scB[256]; // scan path (4 KB)
    const int tid = threadIdx.x;
    const int b = blockIdx.x;

    if (b >= 80) {
        // ---- windowed scatter: thread owns nodes {(q*256+tid)*4+j} (coalesced)
        const int j = b - 80;     // 0..31
        int ty[32];
        #pragma unroll
        for (int q = 0; q < 8; ++q) {
            int4 v = *(const int4*)(nt + ((q << 8) + tid) * 4);
            ty[q * 4 + 0] = v.x; ty[q * 4 + 1] = v.y;
            ty[q * 4 + 2] = v.z; ty[q * 4 + 3] = v.w;
        }
        int cnt[8];
        #pragma unroll
        for (int tt = 0; tt < 8; ++tt) cnt[tt] = 0;
        #pragma unroll
        for (int k = 0; k < 32; ++k) {
            int t0 = ty[k];
            #pragma unroll
            for (int tt = 0; tt < 8; ++tt) cnt[tt] += (t0 == tt);
        }
        unsigned long long lo = (unsigned long long)cnt[0]
                              | ((unsigned long long)cnt[1] << 16)
                              | ((unsigned long long)cnt[2] << 32)
                              | ((unsigned long long)cnt[3] << 48);
        unsigned long long hi = (unsigned long long)cnt[4]
                              | ((unsigned long long)cnt[5] << 16)
                              | ((unsigned long long)cnt[6] << 32)
                              | ((unsigned long long)cnt[7] << 48);
        scA[tid] = lo; scB[tid] = hi;
        #pragma unroll
        for (int ofs = 1; ofs < 256; ofs <<= 1) {
            __syncthreads();
            unsigned long long aLo = (tid >= ofs) ? scA[tid - ofs] : 0ull;
            unsigned long long aHi = (tid >= ofs) ? scB[tid - ofs] : 0ull;
            __syncthreads();
            scA[tid] += aLo; scB[tid] += aHi;
        }
        __syncthreads();
        if (j == 0 && tid == 255) {
            unsigned long long tLo = scA[255], tHi = scB[255];
            #pragma unroll
            for (int tt = 0; tt < 4; ++tt) {
                cursors[tt]     = (int)((tLo >> (16 * tt)) & 0xFFFFull);
                cursors[tt + 4] = (int)((tHi >> (16 * tt)) & 0xFFFFull);
            }
        }
        if ((tid >> 3) == j) {    // this block's 8 owner-threads write 32 entries each
            unsigned long long exLo = scA[tid] - lo, exHi = scB[tid] - hi;
            int P[8], r[8];
            #pragma unroll
            for (int tt = 0; tt < 4; ++tt) {
                P[tt]     = (int)((exLo >> (16 * tt)) & 0xFFFFull);
                P[tt + 4] = (int)((exHi >> (16 * tt)) & 0xFFFFull);
            }
            #pragma unroll
            for (int tt = 0; tt < 8; ++tt) r[tt] = 0;
            #pragma unroll
            for (int k = 0; k < 32; ++k) {
                int t0 = ty[k];
                int nodeid = ((k >> 2) << 10) + (tid << 2) + (k & 3);
                #pragma unroll
                for (int tt = 0; tt < 8; ++tt)
                    if (t0 == tt) { perm[tt * N_NODES + P[tt] + r[tt]] = nodeid; r[tt]++; }
            }
        }
        return;
    }

    // ---- weight prep (blocks 0-79), one 64x64 f32 tile each ----
    const float* src;
    unsigned short* dstBase;
    int srcStride, rowBytes, colBase, rBase;
    if (b < 32) {
        int t = b >> 2, kt = b & 3;
        src = W_att + (((size_t)t * 256 + kt * 64) << 6);
        srcStride = 64;
        dstBase = waT + (size_t)t * 16384;
        rowBytes = 512; colBase = kt * 128; rBase = 0;
    } else {
        int j = b - 32;
        int isWh = (j >= 24); if (isWh) j -= 24;
        int t = j / 3, nt2 = j - t * 3;
        src = (isWh ? W_hid : W_in) + (size_t)t * 64 * 192 + nt2 * 64;
        srcStride = 192;
        dstBase = (isWh ? whT : wiT) + (size_t)t * 12288;
        rowBytes = 128; colBase = 0; rBase = nt2 * 64;
    }

    #pragma unroll
    for (int e = 0; e < 4; ++e) {
        int f = e * 256 + tid;
        int kk = f >> 4, c = (f & 15) << 2;
        float4 v = *(const float4*)(src + kk * srcStride + c);
        Lf[kk][c] = v.x; Lf[kk][c + 1] = v.y; Lf[kk][c + 2] = v.z; Lf[kk][c + 3] = v.w;
    }
    __syncthreads();

    #pragma unroll
    for (int e = 0; e < 2; ++e) {
        int q = e * 256 + tid;
        int ko8 = q >> 6, rl = q & 63;
        int r = rBase + rl;
        unsigned short tmp[8];
        #pragma unroll
        for (int j2 = 0; j2 < 8; ++j2)
            tmp[j2] = f2bf(Lf[ko8 * 8 + j2][rl]);
        int4 wv;
        wv.x = (int)tmp[0] | ((int)tmp[1] << 16);
        wv.y = (int)tmp[2] | ((int)tmp[3] << 16);
        wv.z = (int)tmp[4] | ((int)tmp[5] << 16);
        wv.w = (int)tmp[6] | ((int)tmp[7] << 16);
        int B = r * rowBytes + colBase + ((ko8 << 4) ^ ((r & 7) << 4));
        *(int4*)((char*)dstBase + B) = wv;
    }
}

__global__ __launch_bounds__(256, 1) void fused_rgnn(
    const float* __restrict__ agg, const float* __restrict__ h,
    const int* __restrict__ cursors, const int* __restrict__ perm,
    const unsigned short* __restrict__ waT, const unsigned short* __restrict__ wiT,
    const unsigned short* __restrict__ whT,
    const float* __restrict__ b_att, const float* __restrict__ b_in,
    const float* __restrict__ b_hid, float* __restrict__ out)
{
    __shared__ __align__(16) char sm_[L_TOT];
    char* sm = sm_;
    const int tid = threadIdx.x;
    const int b = blockIdx.x;

    // (type, chunk) from cursors prefix, BM=64 chunks.
    const int4 c0 = *(const int4*)cursors;
    const int4 c1 = *(const int4*)(cursors + 4);
    const int cntArr[8] = {c0.x, c0.y, c0.z, c0.w, c1.x, c1.y, c1.z, c1.w};
    int t = -1, chunk = 0, tcnt = 0, acc = 0;
    #pragma unroll
    for (int tt = 0; tt < T_TYPES; ++tt) {
        int nc = (cntArr[tt] + BM - 1) >> 6;
        if (t < 0 && b < acc + nc) { t = tt; chunk = b - acc; tcnt = cntArr[tt]; }
        acc += nc;
    }
    if (t < 0) return;
    const int m0 = chunk * BM;
    const int mcnt = min(BM, tcnt - m0);

    const int lane = tid & 63;
    const int w = tid >> 6;
    const int lr = lane & 15;
    const int lk = lane >> 4;
    const int col = (w << 4) + lr;
    const int swzA = (lr & 7) << 4;

    // Biases.
    const float ba  = b_att[(t << 6) + col];
    const float bir = b_in [t * G3 + col];
    const float biz = b_in [t * G3 + 64 + col];
    const float bnn = b_in [t * G3 + 128 + col];
    const float bhr = b_hid[t * G3 + col];
    const float bhz = b_hid[t * G3 + 64 + col];
    const float bhn = b_hid[t * G3 + 128 + col];

    // --- per-thread perm gathers (no barrier needed) ---
    const int kx = (tid & 31) << 3;   // 8 floats of the 256-wide X row
    const int nbx = tid >> 5;         // X nodes: nbx + 8s, s<8
    int xg[8];
    #pragma unroll
    for (int s = 0; s < 8; ++s) {
        int node = nbx + (s << 3);
        xg[s] = (node < mcnt) ? perm[t * N_NODES + m0 + node] : -1;
    }
    const int nh = tid >> 3;          // H nodes: nh + 32s, s<2
    const int kh = (tid & 7) << 3;
    int hg[2];
    #pragma unroll
    for (int s = 0; s < 2; ++s) {
        int node = nh + (s << 5);
        hg[s] = (node < mcnt) ? perm[t * N_NODES + m0 + node] : -1;
    }

    // --- issue X/H f32 loads ---
    float4 xv[8][2];
    #pragma unroll
    for (int s = 0; s < 8; ++s) {
        if (xg[s] >= 0) {
            const float* p = agg + (size_t)xg[s] * HIN + kx;
            xv[s][0] = *(const float4*)p;
            xv[s][1] = *(const float4*)(p + 4);
        } else {
            xv[s][0] = make_float4(0.f, 0.f, 0.f, 0.f);
            xv[s][1] = make_float4(0.f, 0.f, 0.f, 0.f);
        }
    }
    float4 hv[2][2];
    #pragma unroll
    for (int s = 0; s < 2; ++s) {
        if (hg[s] >= 0) {
            const float* p = h + (size_t)hg[s] * OUTF + kh;
            hv[s][0] = *(const float4*)p;
            hv[s][1] = *(const float4*)(p + 4);
        } else {
            hv[s][0] = make_float4(0.f, 0.f, 0.f, 0.f);
            hv[s][1] = make_float4(0.f, 0.f, 0.f, 0.f);
        }
    }

    // --- issue weight global->LDS DMA (20 x 16B/lane, stays in flight) ---
    {
        const char* was = (const char*)(waT + (size_t)t * 16384);
        const char* wis = (const char*)(wiT + (size_t)t * 12288);
        const char* whs = (const char*)(whT + (size_t)t * 12288);
        #pragma unroll
        for (int r = 0; r < 8; ++r) {     // 32KB = 32 x 1KB chunks
            int c = (r << 2) + w;
            GLD_LDS16(was + (c << 10) + (lane << 4), sm + L_WAS + (c << 10));
        }
        #pragma unroll
        for (int r = 0; r < 6; ++r) {     // 24KB = 24 x 1KB chunks
            int c = (r << 2) + w;
            GLD_LDS16(wis + (c << 10) + (lane << 4), sm + L_WIS + (c << 10));
            GLD_LDS16(whs + (c << 10) + (lane << 4), sm + L_WHS + (c << 10));
        }
    }

    // --- consume X: relu -> bf16 -> swizzled LDS ---
    #pragma unroll
    for (int s = 0; s < 8; ++s) {
        int node = nbx + (s << 3);
        float4 a = xv[s][0], bq = xv[s][1];
        int4 wv;
        wv.x = pack2bf(fmaxf(a.x, 0.f), fmaxf(a.y, 0.f));
        wv.y = pack2bf(fmaxf(a.z, 0.f), fmaxf(a.w, 0.f));
        wv.z = pack2bf(fmaxf(bq.x, 0.f), fmaxf(bq.y, 0.f));
        wv.w = pack2bf(fmaxf(bq.z, 0.f), fmaxf(bq.w, 0.f));
        *(int4*)(sm + L_XS + (node << 9) + ((kx << 1) ^ ((node & 7) << 4))) = wv;
    }
    // --- consume H: bf16 swizzled + idx table ---
    #pragma unroll
    for (int s = 0; s < 2; ++s) {
        int node = nh + (s << 5);
        int4 wv;
        wv.x = pack2bf(hv[s][0].x, hv[s][0].y);
        wv.y = pack2bf(hv[s][0].z, hv[s][0].w);
        wv.z = pack2bf(hv[s][1].x, hv[s][1].y);
        wv.w = pack2bf(hv[s][1].z, hv[s][1].w);
        *(int4*)(sm + L_HS + (node << 7) + ((kh << 1) ^ ((node & 7) << 4))) = wv;
        if ((tid & 7) == 0) ((int*)(sm + L_IDX))[node] = hg[s];
    }
    __syncthreads();   // drains weight DMA + LDS writes

    // --- phase 2: Y = relu(X @ Wa + ba), 4 row-tiles per wave ---
    f32x4 yacc[4];
    #pragma unroll
    for (int m = 0; m < 4; ++m) yacc[m] = (f32x4){0.f, 0.f, 0.f, 0.f};
    #pragma unroll
    for (int ks = 0; ks < 8; ++ks) {
        int off = ((ks << 6) + (lk << 4)) ^ swzA;
        bf16x8 bb = *(const bf16x8*)(sm + L_WAS + (((w << 4) + lr) << 9) + off);
        #pragma unroll
        for (int m = 0; m < 4; ++m) {
            bf16x8 am = *(const bf16x8*)(sm + L_XS + (((m << 4) + lr) << 9) + off);
            yacc[m] = __builtin_amdgcn_mfma_f32_16x16x32_bf16(am, bb, yacc[m], 0, 0, 0);
        }
    }
    #pragma unroll
    for (int m = 0; m < 4; ++m) {
        #pragma unroll
        for (int r = 0; r < 4; ++r) {
            int row = (m << 4) + (lk << 2) + r;
            float y = fmaxf(yacc[m][r] + ba, 0.f);
            *(unsigned short*)(sm + L_YS + (row << 7) +
                               ((col << 1) ^ ((row & 7) << 4))) = f2bf(y);
        }
    }
    __syncthreads();

    // --- phase 3: gi = Y @ Wi, gh = H @ Wh ---
    f32x4 gi[4][3], gh[4][3];
    #pragma unroll
    for (int m = 0; m < 4; ++m)
        #pragma unroll
        for (int g = 0; g < 3; ++g) {
            gi[m][g] = (f32x4){0.f, 0.f, 0.f, 0.f};
            gh[m][g] = (f32x4){0.f, 0.f, 0.f, 0.f};
        }
    #pragma unroll
    for (int ks = 0; ks < 2; ++ks) {
        int off = ((ks << 6) + (lk << 4)) ^ swzA;
        bf16x8 ay[4], ah[4];
        #pragma unroll
        for (int m = 0; m < 4; ++m) {
            ay[m] = *(const bf16x8*)(sm + L_YS + (((m << 4) + lr) << 7) + off);
            ah[m] = *(const bf16x8*)(sm + L_HS + (((m << 4) + lr) << 7) + off);
        }
        #pragma unroll
        for (int g = 0; g < 3; ++g) {
            int brow = (g << 6) + col;
            bf16x8 bi = *(const bf16x8*)(sm + L_WIS + (brow << 7) + off);
            bf16x8 bh = *(const bf16x8*)(sm + L_WHS + (brow << 7) + off);
            #pragma unroll
            for (int m = 0; m < 4; ++m) {
                gi[m][g] = __builtin_amdgcn_mfma_f32_16x16x32_bf16(ay[m], bi, gi[m][g], 0, 0, 0);
                gh[m][g] = __builtin_amdgcn_mfma_f32_16x16x32_bf16(ah[m], bh, gh[m][g], 0, 0, 0);
            }
        }
    }

    // --- epilogue: GRU gates (f32) + scatter store; h re-read from global ---
    const int* idxp = (const int*)(sm + L_IDX);
    #pragma unroll
    for (int m = 0; m < 4; ++m) {
        #pragma unroll
        for (int r = 0; r < 4; ++r) {
            int node = (m << 4) + (lk << 2) + r;
            if (node < mcnt) {
                int gidx = idxp[node];
                float rv = gi[m][0][r] + bir + gh[m][0][r] + bhr;
                float rg = 1.f / (1.f + __expf(-rv));
                float zv = gi[m][1][r] + biz + gh[m][1][r] + bhz;
                float zg = 1.f / (1.f + __expf(-zv));
                float ng = tanhf(gi[m][2][r] + bnn + rg * (gh[m][2][r] + bhn));
                float hold = h[(size_t)gidx * OUTF + col];
                out[(size_t)gidx * OUTF + col] = (1.f - zg) * ng + zg * hold;
            }
        }
    }
}

extern "C" void kernel_launch(void* const* d_in, const int* in_sizes, int n_in,
                              void* d_out, int out_size, void* d_ws, size_t ws_size,
                              hipStream_t stream) {
    const float* agg   = (const float*)d_in[0];
    const float* h     = (const float*)d_in[1];
    const int*   ntype = (const int*)d_in[2];
    const float* W_att = (const float*)d_in[3];
    const float* b_att = (const float*)d_in[4];
    const float* W_in  = (const float*)d_in[5];
    const float* W_hid = (const float*)d_in[6];
    const float* b_in  = (const float*)d_in[7];
    const float* b_hid = (const float*)d_in[8];
    float* out = (float*)d_out;

    char* ws = (char*)d_ws;
    int* cursors = (int*)(ws + WS_CURS);
    int* perm = (int*)(ws + WS_PERM);
    unsigned short* waT = (unsigned short*)(ws + WS_WAT);
    unsigned short* wiT = (unsigned short*)(ws + WS_WIT);
    unsigned short* whT = (unsigned short*)(ws + WS_WHT);

    prep_and_scatter<<<112, 256, 0, stream>>>(W_att, W_in, W_hid, ntype,
                                              cursors, perm, waT, wiT, whT);
    fused_rgnn<<<MAXBLK, 256, 0, stream>>>(agg, h, cursors, perm,
        waT, wiT, whT, b_att, b_in, b_hid, out);
}

// Round 11
// 23.031 us; speedup vs baseline: 1.4070x; 1.4070x over previous
//
#include <hip/hip_runtime.h>

#define N_NODES 8192
#define T_TYPES 8
#define HIN 256     // H*IN
#define OUTF 64
#define G3 192      // 3*OUT
#define BM 64       // nodes per fused block
#define MAXBLK 135  // 8192/64 + up to 7 partial chunks
#define SCAT_BLKS 32

typedef __attribute__((ext_vector_type(8))) __bf16 bf16x8;
typedef __attribute__((ext_vector_type(4))) float f32x4;

// workspace byte offsets
#define WS_CURS 0
#define WS_PERM 256
#define WS_WAT  (256 + 262144)           // 8 types * 32768 B (bf16 [64][256], pre-swizzled)
#define WS_WIT  (WS_WAT + 262144)        // 8 types * 24576 B (bf16 [192][64], pre-swizzled)
#define WS_WHT  (WS_WIT + 196608)        // 8 types * 24576 B
#define WS_CNT  (WS_WHT + 196608)        // 32 * 8 ints

// LDS byte offsets (fused kernel, BM=64)
#define L_XS  0        // X [64][256] bf16, swizzled          32768
#define L_WAS 32768    // WaT [64][256] bf16, swizzled        32768
#define L_WIS 65536    // WiT [192][64] bf16, swizzled        24576
#define L_WHS 90112    // WhT [192][64] bf16, swizzled        24576
#define L_YS  114688   // Y [64][64] bf16, swizzled            8192
#define L_HS  122880   // H [64][64] bf16, swizzled            8192
#define L_HF  131072   // H [64][64] f32, plain               16384
#define L_IDX 147456   // 64 ints                               256
#define L_TOT 147712

#define GLD_LDS16(g, l) __builtin_amdgcn_global_load_lds( \
    (const __attribute__((address_space(1))) void*)(g),   \
    (__attribute__((address_space(3))) void*)(l), 16, 0, 0)

__device__ __forceinline__ unsigned short f2bf(float f) {
    unsigned u = __float_as_uint(f);
    return (unsigned short)((u + 0x7FFFu + ((u >> 16) & 1u)) >> 16);
}
__device__ __forceinline__ int pack2bf(float a, float b) {
    return (int)f2bf(a) | ((int)f2bf(b) << 16);
}

// K1 (R5-proven): blocks 0-79 = weight transpose/bf16/pre-swizzle;
//                 blocks 80-111 = per-block type histograms (LDS atomics only).
__global__ __launch_bounds__(256) void prep_and_count(
    const float* __restrict__ W_att, const float* __restrict__ W_in,
    const float* __restrict__ W_hid, const int* __restrict__ nt,
    int* __restrict__ counts,
    unsigned short* __restrict__ waT, unsigned short* __restrict__ wiT,
    unsigned short* __restrict__ whT)
{
    __shared__ float Lf[64][68];   // prep path
    __shared__ int hist[8];        // count path
    const int tid = threadIdx.x;
    const int b = blockIdx.x;

    if (b >= 80) {                 // --- histogram blocks ---
        int j = b - 80;
        if (tid < 8) hist[tid] = 0;
        __syncthreads();
        atomicAdd(&hist[nt[j * 256 + tid]], 1);    // LDS atomic
        __syncthreads();
        if (tid < 8) counts[j * 8 + tid] = hist[tid];
        return;
    }

    const float* src;
    unsigned short* dstBase;
    int srcStride, rowBytes, colBase, rBase;

    if (b < 32) {
        int t = b >> 2, kt = b & 3;
        src = W_att + (((size_t)t * 256 + kt * 64) << 6);
        srcStride = 64;
        dstBase = waT + (size_t)t * 16384;
        rowBytes = 512; colBase = kt * 128; rBase = 0;
    } else {
        int j = b - 32;
        int isWh = (j >= 24); if (isWh) j -= 24;
        int t = j / 3, nt2 = j - t * 3;
        src = (isWh ? W_hid : W_in) + (size_t)t * 64 * 192 + nt2 * 64;
        srcStride = 192;
        dstBase = (isWh ? whT : wiT) + (size_t)t * 12288;
        rowBytes = 128; colBase = 0; rBase = nt2 * 64;
    }

    #pragma unroll
    for (int e = 0; e < 4; ++e) {
        int f = e * 256 + tid;            // float4 index within the 64x64 tile
        int kk = f >> 4, c = (f & 15) << 2;
        float4 v = *(const float4*)(src + kk * srcStride + c);
        Lf[kk][c] = v.x; Lf[kk][c + 1] = v.y; Lf[kk][c + 2] = v.z; Lf[kk][c + 3] = v.w;
    }
    __syncthreads();

    #pragma unroll
    for (int e = 0; e < 2; ++e) {
        int q = e * 256 + tid;
        int ko8 = q >> 6, rl = q & 63;
        int r = rBase + rl;
        unsigned short tmp[8];
        #pragma unroll
        for (int j2 = 0; j2 < 8; ++j2)
            tmp[j2] = f2bf(Lf[ko8 * 8 + j2][rl]);
        int4 wv;
        wv.x = (int)tmp[0] | ((int)tmp[1] << 16);
        wv.y = (int)tmp[2] | ((int)tmp[3] << 16);
        wv.z = (int)tmp[4] | ((int)tmp[5] << 16);
        wv.w = (int)tmp[6] | ((int)tmp[7] << 16);
        int B = r * rowBytes + colBase + ((ko8 << 4) ^ ((r & 7) << 4));
        *(int4*)((char*)dstBase + B) = wv;
    }
}

// K2 (R5-proven): atomic-free scatter via the 1 KB count table.
__global__ __launch_bounds__(256) void scatter_pass(
    const int* __restrict__ nt, const int* __restrict__ counts,
    int* __restrict__ cursors, int* __restrict__ perm)
{
    __shared__ int tbl[SCAT_BLKS * 8];
    __shared__ int cur[8];
    const int tid = threadIdx.x;
    const int j = blockIdx.x;

    tbl[tid] = counts[tid];   // 256 == SCAT_BLKS*8
    __syncthreads();
    if (tid < 8) {
        int base = 0, tot = 0;
        #pragma unroll
        for (int k = 0; k < SCAT_BLKS; ++k) {
            int c = tbl[k * 8 + tid];
            if (k < j) base += c;
            tot += c;
        }
        cur[tid] = base;
        if (j == 0) cursors[tid] = tot;
    }
    __syncthreads();
    int i = j * 256 + tid;
    int t = nt[i];
    int pos = atomicAdd(&cur[t], 1);      // LDS atomic
    perm[t * N_NODES + pos] = i;
}

// K3: fused, BM=64 -> 135 blocks, single dispatch round at 1 block/CU.
__global__ __launch_bounds__(256, 1) void fused_rgnn(
    const float* __restrict__ agg, const float* __restrict__ h,
    const int* __restrict__ cursors, const int* __restrict__ perm,
    const unsigned short* __restrict__ waT, const unsigned short* __restrict__ wiT,
    const unsigned short* __restrict__ whT,
    const float* __restrict__ b_att, const float* __restrict__ b_in,
    const float* __restrict__ b_hid, float* __restrict__ out)
{
    __shared__ __align__(16) char sm_[L_TOT];
    char* sm = sm_;
    const int tid = threadIdx.x;
    const int b = blockIdx.x;

    // (type, chunk) from cursors prefix, BM=64 chunks.
    const int4 c0 = *(const int4*)cursors;
    const int4 c1 = *(const int4*)(cursors + 4);
    const int cntArr[8] = {c0.x, c0.y, c0.z, c0.w, c1.x, c1.y, c1.z, c1.w};
    int t = -1, chunk = 0, tcnt = 0, acc = 0;
    #pragma unroll
    for (int tt = 0; tt < T_TYPES; ++tt) {
        int nc = (cntArr[tt] + BM - 1) >> 6;
        if (t < 0 && b < acc + nc) { t = tt; chunk = b - acc; tcnt = cntArr[tt]; }
        acc += nc;
    }
    if (t < 0) return;
    const int m0 = chunk * BM;
    const int mcnt = min(BM, tcnt - m0);

    const int lane = tid & 63;
    const int w = tid >> 6;
    const int lr = lane & 15;
    const int lk = lane >> 4;
    const int col = (w << 4) + lr;
    const int swzA = (lr & 7) << 4;

    // Biases (independent, issued early).
    const float ba  = b_att[(t << 6) + col];
    const float bir = b_in [t * G3 + col];
    const float biz = b_in [t * G3 + 64 + col];
    const float bnn = b_in [t * G3 + 128 + col];
    const float bhr = b_hid[t * G3 + col];
    const float bhz = b_hid[t * G3 + 64 + col];
    const float bhn = b_hid[t * G3 + 128 + col];

    // --- per-thread perm gathers ---
    const int kx = (tid & 31) << 3;   // 8 floats of the 256-wide X row
    const int nbx = tid >> 5;         // X nodes: nbx + 8s, s<8
    int xg[8];
    #pragma unroll
    for (int s = 0; s < 8; ++s) {
        int node = nbx + (s << 3);
        xg[s] = (node < mcnt) ? perm[t * N_NODES + m0 + node] : -1;
    }
    const int nh = tid >> 3;          // H nodes: nh + 32s, s<2
    const int kh = (tid & 7) << 3;
    int hg[2];
    #pragma unroll
    for (int s = 0; s < 2; ++s) {
        int node = nh + (s << 5);
        hg[s] = (node < mcnt) ? perm[t * N_NODES + m0 + node] : -1;
    }

    // --- issue X/H f32 loads ---
    float4 xv[8][2];
    #pragma unroll
    for (int s = 0; s < 8; ++s) {
        if (xg[s] >= 0) {
            const float* p = agg + (size_t)xg[s] * HIN + kx;
            xv[s][0] = *(const float4*)p;
            xv[s][1] = *(const float4*)(p + 4);
        } else {
            xv[s][0] = make_float4(0.f, 0.f, 0.f, 0.f);
            xv[s][1] = make_float4(0.f, 0.f, 0.f, 0.f);
        }
    }
    float4 hv[2][2];
    #pragma unroll
    for (int s = 0; s < 2; ++s) {
        if (hg[s] >= 0) {
            const float* p = h + (size_t)hg[s] * OUTF + kh;
            hv[s][0] = *(const float4*)p;
            hv[s][1] = *(const float4*)(p + 4);
        } else {
            hv[s][0] = make_float4(0.f, 0.f, 0.f, 0.f);
            hv[s][1] = make_float4(0.f, 0.f, 0.f, 0.f);
        }
    }

    // --- issue weight global->LDS DMA (20 x 16B/lane, stays in flight) ---
    {
        const char* was = (const char*)(waT + (size_t)t * 16384);
        const char* wis = (const char*)(wiT + (size_t)t * 12288);
        const char* whs = (const char*)(whT + (size_t)t * 12288);
        #pragma unroll
        for (int r = 0; r < 8; ++r) {     // 32KB = 32 x 1KB chunks
            int c = (r << 2) + w;
            GLD_LDS16(was + (c << 10) + (lane << 4), sm + L_WAS + (c << 10));
        }
        #pragma unroll
        for (int r = 0; r < 6; ++r) {     // 24KB = 24 x 1KB chunks
            int c = (r << 2) + w;
            GLD_LDS16(wis + (c << 10) + (lane << 4), sm + L_WIS + (c << 10));
            GLD_LDS16(whs + (c << 10) + (lane << 4), sm + L_WHS + (c << 10));
        }
    }

    // --- consume X: relu -> bf16 -> swizzled LDS ---
    #pragma unroll
    for (int s = 0; s < 8; ++s) {
        int node = nbx + (s << 3);
        float4 a = xv[s][0], bq = xv[s][1];
        int4 wv;
        wv.x = pack2bf(fmaxf(a.x, 0.f), fmaxf(a.y, 0.f));
        wv.y = pack2bf(fmaxf(a.z, 0.f), fmaxf(a.w, 0.f));
        wv.z = pack2bf(fmaxf(bq.x, 0.f), fmaxf(bq.y, 0.f));
        wv.w = pack2bf(fmaxf(bq.z, 0.f), fmaxf(bq.w, 0.f));
        *(int4*)(sm + L_XS + (node << 9) + ((kx << 1) ^ ((node & 7) << 4))) = wv;
    }
    // --- consume H: f32 copy + bf16 swizzled + idx table ---
    #pragma unroll
    for (int s = 0; s < 2; ++s) {
        int node = nh + (s << 5);
        *(float4*)(sm + L_HF + (node << 8) + (kh << 2)) = hv[s][0];
        *(float4*)(sm + L_HF + (node << 8) + (kh << 2) + 16) = hv[s][1];
        int4 wv;
        wv.x = pack2bf(hv[s][0].x, hv[s][0].y);
        wv.y = pack2bf(hv[s][0].z, hv[s][0].w);
        wv.z = pack2bf(hv[s][1].x, hv[s][1].y);
        wv.w = pack2bf(hv[s][1].z, hv[s][1].w);
        *(int4*)(sm + L_HS + (node << 7) + ((kh << 1) ^ ((node & 7) << 4))) = wv;
        if ((tid & 7) == 0) ((int*)(sm + L_IDX))[node] = hg[s];
    }
    __syncthreads();   // drains weight DMA + LDS writes

    // --- phase 2: Y = relu(X @ Wa + ba), 4 row-tiles per wave ---
    f32x4 yacc[4];
    #pragma unroll
    for (int m = 0; m < 4; ++m) yacc[m] = (f32x4){0.f, 0.f, 0.f, 0.f};
    #pragma unroll
    for (int ks = 0; ks < 8; ++ks) {
        int off = ((ks << 6) + (lk << 4)) ^ swzA;
        bf16x8 bb = *(const bf16x8*)(sm + L_WAS + (((w << 4) + lr) << 9) + off);
        #pragma unroll
        for (int m = 0; m < 4; ++m) {
            bf16x8 am = *(const bf16x8*)(sm + L_XS + (((m << 4) + lr) << 9) + off);
            yacc[m] = __builtin_amdgcn_mfma_f32_16x16x32_bf16(am, bb, yacc[m], 0, 0, 0);
        }
    }
    #pragma unroll
    for (int m = 0; m < 4; ++m) {
        #pragma unroll
        for (int r = 0; r < 4; ++r) {
            int row = (m << 4) + (lk << 2) + r;
            float y = fmaxf(yacc[m][r] + ba, 0.f);
            *(unsigned short*)(sm + L_YS + (row << 7) +
                               ((col << 1) ^ ((row & 7) << 4))) = f2bf(y);
        }
    }
    __syncthreads();

    // --- phase 3: gi = Y @ Wi, gh = H @ Wh ---
    f32x4 gi[4][3], gh[4][3];
    #pragma unroll
    for (int m = 0; m < 4; ++m)
        #pragma unroll
        for (int g = 0; g < 3; ++g) {
            gi[m][g] = (f32x4){0.f, 0.f, 0.f, 0.f};
            gh[m][g] = (f32x4){0.f, 0.f, 0.f, 0.f};
        }
    #pragma unroll
    for (int ks = 0; ks < 2; ++ks) {
        int off = ((ks << 6) + (lk << 4)) ^ swzA;
        bf16x8 ay[4], ah[4];
        #pragma unroll
        for (int m = 0; m < 4; ++m) {
            ay[m] = *(const bf16x8*)(sm + L_YS + (((m << 4) + lr) << 7) + off);
            ah[m] = *(const bf16x8*)(sm + L_HS + (((m << 4) + lr) << 7) + off);
        }
        #pragma unroll
        for (int g = 0; g < 3; ++g) {
            int brow = (g << 6) + col;
            bf16x8 bi = *(const bf16x8*)(sm + L_WIS + (brow << 7) + off);
            bf16x8 bh = *(const bf16x8*)(sm + L_WHS + (brow << 7) + off);
            #pragma unroll
            for (int m = 0; m < 4; ++m) {
                gi[m][g] = __builtin_amdgcn_mfma_f32_16x16x32_bf16(ay[m], bi, gi[m][g], 0, 0, 0);
                gh[m][g] = __builtin_amdgcn_mfma_f32_16x16x32_bf16(ah[m], bh, gh[m][g], 0, 0, 0);
            }
        }
    }

    // --- epilogue: GRU gates (f32) + scatter store ---
    const int* idxp = (const int*)(sm + L_IDX);
    #pragma unroll
    for (int m = 0; m < 4; ++m) {
        #pragma unroll
        for (int r = 0; r < 4; ++r) {
            int node = (m << 4) + (lk << 2) + r;
            if (node < mcnt) {
                int gidx = idxp[node];
                float rv = gi[m][0][r] + bir + gh[m][0][r] + bhr;
                float rg = 1.f / (1.f + __expf(-rv));
                float zv = gi[m][1][r] + biz + gh[m][1][r] + bhz;
                float zg = 1.f / (1.f + __expf(-zv));
                float ng = tanhf(gi[m][2][r] + bnn + rg * (gh[m][2][r] + bhn));
                float hold = *(const float*)(sm + L_HF + (node << 8) + (col << 2));
                out[(size_t)gidx * OUTF + col] = (1.f - zg) * ng + zg * hold;
            }
        }
    }
}

extern "C" void kernel_launch(void* const* d_in, const int* in_sizes, int n_in,
                              void* d_out, int out_size, void* d_ws, size_t ws_size,
                              hipStream_t stream) {
    const float* agg   = (const float*)d_in[0];
    const float* h     = (const float*)d_in[1];
    const int*   ntype = (const int*)d_in[2];
    const float* W_att = (const float*)d_in[3];
    const float* b_att = (const float*)d_in[4];
    const float* W_in  = (const float*)d_in[5];
    const float* W_hid = (const float*)d_in[6];
    const float* b_in  = (const float*)d_in[7];
    const float* b_hid = (const float*)d_in[8];
    float* out = (float*)d_out;

    char* ws = (char*)d_ws;
    int* cursors = (int*)(ws + WS_CURS);
    int* perm = (int*)(ws + WS_PERM);
    unsigned short* waT = (unsigned short*)(ws + WS_WAT);
    unsigned short* wiT = (unsigned short*)(ws + WS_WIT);
    unsigned short* whT = (unsigned short*)(ws + WS_WHT);
    int* counts = (int*)(ws + WS_CNT);

    prep_and_count<<<112, 256, 0, stream>>>(W_att, W_in, W_hid, ntype, counts, waT, wiT, whT);
    scatter_pass<<<SCAT_BLKS, 256, 0, stream>>>(ntype, counts, cursors, perm);
    fused_rgnn<<<MAXBLK, 256, 0, stream>>>(agg, h, cursors, perm,
        waT, wiT, whT, b_att, b_in, b_hid, out);
}

// Round 12
// 20.763 us; speedup vs baseline: 1.5607x; 1.1092x over previous
//
#include <hip/hip_runtime.h>

#define N_NODES 8192
#define T_TYPES 8
#define HIN 256     // H*IN
#define OUTF 64
#define G3 192      // 3*OUT
#define BM 64       // nodes per fused block
#define MAXBLK 135  // 8192/64 + up to 7 partial chunks
#define SCAT_BLKS 32

typedef __attribute__((ext_vector_type(8))) __bf16 bf16x8;
typedef __attribute__((ext_vector_type(4))) float f32x4;

// workspace byte offsets
#define WS_CURS 0
#define WS_PERM 256
#define WS_WAT  (256 + 262144)           // 8 types * 32768 B (bf16 [64][256], pre-swizzled)
#define WS_WIT  (WS_WAT + 262144)        // 8 types * 24576 B (bf16 [192][64], pre-swizzled)
#define WS_WHT  (WS_WIT + 196608)        // 8 types * 24576 B
#define WS_CNT  (WS_WHT + 196608)        // 32 * 8 ints

// LDS byte offsets (fused kernel, BM=64)
#define L_XS  0        // X [64][256] bf16, swizzled          32768
#define L_WAS 32768    // WaT [64][256] bf16, swizzled        32768
#define L_WIS 65536    // WiT [192][64] bf16, swizzled        24576
#define L_WHS 90112    // WhT [192][64] bf16, swizzled        24576
#define L_YS  114688   // Y [64][64] bf16, swizzled            8192
#define L_HS  122880   // H [64][64] bf16, swizzled            8192
#define L_HF  131072   // H [64][64] f32, plain               16384
#define L_IDX 147456   // 64 ints                               256
#define L_TOT 147712

#define GLD_LDS16(g, l) __builtin_amdgcn_global_load_lds( \
    (const __attribute__((address_space(1))) void*)(g),   \
    (__attribute__((address_space(3))) void*)(l), 16, 0, 0)

__device__ __forceinline__ unsigned short f2bf(float f) {
    unsigned u = __float_as_uint(f);
    return (unsigned short)((u + 0x7FFFu + ((u >> 16) & 1u)) >> 16);
}
__device__ __forceinline__ int pack2bf(float a, float b) {
    return (int)f2bf(a) | ((int)f2bf(b) << 16);
}

// K1 (R5-proven, verbatim): blocks 0-79 = weight transpose/bf16/pre-swizzle;
//                           blocks 80-111 = per-block type histograms.
__global__ __launch_bounds__(256) void prep_and_count(
    const float* __restrict__ W_att, const float* __restrict__ W_in,
    const float* __restrict__ W_hid, const int* __restrict__ nt,
    int* __restrict__ counts,
    unsigned short* __restrict__ waT, unsigned short* __restrict__ wiT,
    unsigned short* __restrict__ whT)
{
    __shared__ float Lf[64][68];   // prep path
    __shared__ int hist[8];        // count path
    const int tid = threadIdx.x;
    const int b = blockIdx.x;

    if (b >= 80) {                 // --- histogram blocks ---
        int j = b - 80;
        if (tid < 8) hist[tid] = 0;
        __syncthreads();
        atomicAdd(&hist[nt[j * 256 + tid]], 1);    // LDS atomic
        __syncthreads();
        if (tid < 8) counts[j * 8 + tid] = hist[tid];
        return;
    }

    const float* src;
    unsigned short* dstBase;
    int srcStride, rowBytes, colBase, rBase;

    if (b < 32) {
        int t = b >> 2, kt = b & 3;
        src = W_att + (((size_t)t * 256 + kt * 64) << 6);
        srcStride = 64;
        dstBase = waT + (size_t)t * 16384;
        rowBytes = 512; colBase = kt * 128; rBase = 0;
    } else {
        int j = b - 32;
        int isWh = (j >= 24); if (isWh) j -= 24;
        int t = j / 3, nt2 = j - t * 3;
        src = (isWh ? W_hid : W_in) + (size_t)t * 64 * 192 + nt2 * 64;
        srcStride = 192;
        dstBase = (isWh ? whT : wiT) + (size_t)t * 12288;
        rowBytes = 128; colBase = 0; rBase = nt2 * 64;
    }

    #pragma unroll
    for (int e = 0; e < 4; ++e) {
        int f = e * 256 + tid;            // float4 index within the 64x64 tile
        int kk = f >> 4, c = (f & 15) << 2;
        float4 v = *(const float4*)(src + kk * srcStride + c);
        Lf[kk][c] = v.x; Lf[kk][c + 1] = v.y; Lf[kk][c + 2] = v.z; Lf[kk][c + 3] = v.w;
    }
    __syncthreads();

    #pragma unroll
    for (int e = 0; e < 2; ++e) {
        int q = e * 256 + tid;
        int ko8 = q >> 6, rl = q & 63;
        int r = rBase + rl;
        unsigned short tmp[8];
        #pragma unroll
        for (int j2 = 0; j2 < 8; ++j2)
            tmp[j2] = f2bf(Lf[ko8 * 8 + j2][rl]);
        int4 wv;
        wv.x = (int)tmp[0] | ((int)tmp[1] << 16);
        wv.y = (int)tmp[2] | ((int)tmp[3] << 16);
        wv.z = (int)tmp[4] | ((int)tmp[5] << 16);
        wv.w = (int)tmp[6] | ((int)tmp[7] << 16);
        int B = r * rowBytes + colBase + ((ko8 << 4) ^ ((r & 7) << 4));
        *(int4*)((char*)dstBase + B) = wv;
    }
}

// K2 (R5-proven, verbatim): atomic-free scatter via the 1 KB count table.
__global__ __launch_bounds__(256) void scatter_pass(
    const int* __restrict__ nt, const int* __restrict__ counts,
    int* __restrict__ cursors, int* __restrict__ perm)
{
    __shared__ int tbl[SCAT_BLKS * 8];
    __shared__ int cur[8];
    const int tid = threadIdx.x;
    const int j = blockIdx.x;

    tbl[tid] = counts[tid];   // 256 == SCAT_BLKS*8
    __syncthreads();
    if (tid < 8) {
        int base = 0, tot = 0;
        #pragma unroll
        for (int k = 0; k < SCAT_BLKS; ++k) {
            int c = tbl[k * 8 + tid];
            if (k < j) base += c;
            tot += c;
        }
        cur[tid] = base;
        if (j == 0) cursors[tid] = tot;
    }
    __syncthreads();
    int i = j * 256 + tid;
    int t = nt[i];
    int pos = atomicAdd(&cur[t], 1);      // LDS atomic
    perm[t * N_NODES + pos] = i;
}

// K3: fused, BM=64, 512 threads (8 waves = 2/SIMD for latency hiding).
// Wave decomposition: wc = w&3 -> col group (16 cols), wrh = w>>2 -> row half.
__global__ __launch_bounds__(512, 1) void fused_rgnn(
    const float* __restrict__ agg, const float* __restrict__ h,
    const int* __restrict__ cursors, const int* __restrict__ perm,
    const unsigned short* __restrict__ waT, const unsigned short* __restrict__ wiT,
    const unsigned short* __restrict__ whT,
    const float* __restrict__ b_att, const float* __restrict__ b_in,
    const float* __restrict__ b_hid, float* __restrict__ out)
{
    __shared__ __align__(16) char sm_[L_TOT];
    char* sm = sm_;
    const int tid = threadIdx.x;
    const int b = blockIdx.x;

    // (type, chunk) from cursors prefix, BM=64 chunks.
    const int4 c0 = *(const int4*)cursors;
    const int4 c1 = *(const int4*)(cursors + 4);
    const int cntArr[8] = {c0.x, c0.y, c0.z, c0.w, c1.x, c1.y, c1.z, c1.w};
    int t = -1, chunk = 0, tcnt = 0, acc = 0;
    #pragma unroll
    for (int tt = 0; tt < T_TYPES; ++tt) {
        int nc = (cntArr[tt] + BM - 1) >> 6;
        if (t < 0 && b < acc + nc) { t = tt; chunk = b - acc; tcnt = cntArr[tt]; }
        acc += nc;
    }
    if (t < 0) return;
    const int m0 = chunk * BM;
    const int mcnt = min(BM, tcnt - m0);

    const int lane = tid & 63;
    const int w = tid >> 6;           // 0..7
    const int wc = w & 3;             // col group
    const int wrh = w >> 2;           // row half
    const int lr = lane & 15;
    const int lk = lane >> 4;
    const int col = (wc << 4) + lr;
    const int swzA = (lr & 7) << 4;

    // Biases (independent, issued early).
    const float ba  = b_att[(t << 6) + col];
    const float bir = b_in [t * G3 + col];
    const float biz = b_in [t * G3 + 64 + col];
    const float bnn = b_in [t * G3 + 128 + col];
    const float bhr = b_hid[t * G3 + col];
    const float bhz = b_hid[t * G3 + 64 + col];
    const float bhn = b_hid[t * G3 + 128 + col];

    // --- per-thread perm gathers ---
    const int kx = (tid & 31) << 3;   // 8 floats of the 256-wide X row
    const int nbx = tid >> 5;         // X nodes: nbx + 16s, s<4
    int xg[4];
    #pragma unroll
    for (int s = 0; s < 4; ++s) {
        int node = nbx + (s << 4);
        xg[s] = (node < mcnt) ? perm[t * N_NODES + m0 + node] : -1;
    }
    const int nh = tid >> 3;          // H node (one per 8 threads), covers 0..63
    const int kh = (tid & 7) << 3;
    int hg = (nh < mcnt) ? perm[t * N_NODES + m0 + nh] : -1;

    // --- issue X/H f32 loads ---
    float4 xv[4][2];
    #pragma unroll
    for (int s = 0; s < 4; ++s) {
        if (xg[s] >= 0) {
            const float* p = agg + (size_t)xg[s] * HIN + kx;
            xv[s][0] = *(const float4*)p;
            xv[s][1] = *(const float4*)(p + 4);
        } else {
            xv[s][0] = make_float4(0.f, 0.f, 0.f, 0.f);
            xv[s][1] = make_float4(0.f, 0.f, 0.f, 0.f);
        }
    }
    float4 hv0, hv1;
    if (hg >= 0) {
        const float* p = h + (size_t)hg * OUTF + kh;
        hv0 = *(const float4*)p;
        hv1 = *(const float4*)(p + 4);
    } else {
        hv0 = make_float4(0.f, 0.f, 0.f, 0.f);
        hv1 = make_float4(0.f, 0.f, 0.f, 0.f);
    }

    // --- issue weight global->LDS DMA (10 x 16B/lane per wave) ---
    {
        const char* was = (const char*)(waT + (size_t)t * 16384);
        const char* wis = (const char*)(wiT + (size_t)t * 12288);
        const char* whs = (const char*)(whT + (size_t)t * 12288);
        #pragma unroll
        for (int r = 0; r < 4; ++r) {     // 32KB = 32 x 1KB chunks / 8 waves
            int c = (r << 3) + w;
            GLD_LDS16(was + (c << 10) + (lane << 4), sm + L_WAS + (c << 10));
        }
        #pragma unroll
        for (int r = 0; r < 3; ++r) {     // 24KB = 24 x 1KB chunks / 8 waves
            int c = (r << 3) + w;
            GLD_LDS16(wis + (c << 10) + (lane << 4), sm + L_WIS + (c << 10));
            GLD_LDS16(whs + (c << 10) + (lane << 4), sm + L_WHS + (c << 10));
        }
    }

    // --- consume X: relu -> bf16 -> swizzled LDS ---
    #pragma unroll
    for (int s = 0; s < 4; ++s) {
        int node = nbx + (s << 4);
        float4 a = xv[s][0], bq = xv[s][1];
        int4 wv;
        wv.x = pack2bf(fmaxf(a.x, 0.f), fmaxf(a.y, 0.f));
        wv.y = pack2bf(fmaxf(a.z, 0.f), fmaxf(a.w, 0.f));
        wv.z = pack2bf(fmaxf(bq.x, 0.f), fmaxf(bq.y, 0.f));
        wv.w = pack2bf(fmaxf(bq.z, 0.f), fmaxf(bq.w, 0.f));
        *(int4*)(sm + L_XS + (node << 9) + ((kx << 1) ^ ((node & 7) << 4))) = wv;
    }
    // --- consume H: f32 copy + bf16 swizzled + idx table ---
    {
        *(float4*)(sm + L_HF + (nh << 8) + (kh << 2)) = hv0;
        *(float4*)(sm + L_HF + (nh << 8) + (kh << 2) + 16) = hv1;
        int4 wv;
        wv.x = pack2bf(hv0.x, hv0.y);
        wv.y = pack2bf(hv0.z, hv0.w);
        wv.z = pack2bf(hv1.x, hv1.y);
        wv.w = pack2bf(hv1.z, hv1.w);
        *(int4*)(sm + L_HS + (nh << 7) + ((kh << 1) ^ ((nh & 7) << 4))) = wv;
        if ((tid & 7) == 0) ((int*)(sm + L_IDX))[nh] = hg;
    }
    __syncthreads();   // drains weight DMA + LDS writes

    // --- phase 2: Y = relu(X @ Wa + ba); wave does 2 row-tiles x 1 col group ---
    f32x4 yacc[2];
    #pragma unroll
    for (int m = 0; m < 2; ++m) yacc[m] = (f32x4){0.f, 0.f, 0.f, 0.f};
    #pragma unroll
    for (int ks = 0; ks < 8; ++ks) {
        int off = ((ks << 6) + (lk << 4)) ^ swzA;
        bf16x8 bb = *(const bf16x8*)(sm + L_WAS + (((wc << 4) + lr) << 9) + off);
        #pragma unroll
        for (int m = 0; m < 2; ++m) {
            int mt = (wrh << 1) + m;
            bf16x8 am = *(const bf16x8*)(sm + L_XS + (((mt << 4) + lr) << 9) + off);
            yacc[m] = __builtin_amdgcn_mfma_f32_16x16x32_bf16(am, bb, yacc[m], 0, 0, 0);
        }
    }
    #pragma unroll
    for (int m = 0; m < 2; ++m) {
        #pragma unroll
        for (int r = 0; r < 4; ++r) {
            int row = (((wrh << 1) + m) << 4) + (lk << 2) + r;
            float y = fmaxf(yacc[m][r] + ba, 0.f);
            *(unsigned short*)(sm + L_YS + (row << 7) +
                               ((col << 1) ^ ((row & 7) << 4))) = f2bf(y);
        }
    }
    __syncthreads();

    // --- phase 3: gi = Y @ Wi, gh = H @ Wh; 2 row-tiles x 3 gates per wave ---
    f32x4 gi[2][3], gh[2][3];
    #pragma unroll
    for (int m = 0; m < 2; ++m)
        #pragma unroll
        for (int g = 0; g < 3; ++g) {
            gi[m][g] = (f32x4){0.f, 0.f, 0.f, 0.f};
            gh[m][g] = (f32x4){0.f, 0.f, 0.f, 0.f};
        }
    #pragma unroll
    for (int ks = 0; ks < 2; ++ks) {
        int off = ((ks << 6) + (lk << 4)) ^ swzA;
        bf16x8 ay[2], ah[2];
        #pragma unroll
        for (int m = 0; m < 2; ++m) {
            int mt = (wrh << 1) + m;
            ay[m] = *(const bf16x8*)(sm + L_YS + (((mt << 4) + lr) << 7) + off);
            ah[m] = *(const bf16x8*)(sm + L_HS + (((mt << 4) + lr) << 7) + off);
        }
        #pragma unroll
        for (int g = 0; g < 3; ++g) {
            int brow = (g << 6) + col;
            bf16x8 bi = *(const bf16x8*)(sm + L_WIS + (brow << 7) + off);
            bf16x8 bh = *(const bf16x8*)(sm + L_WHS + (brow << 7) + off);
            #pragma unroll
            for (int m = 0; m < 2; ++m) {
                gi[m][g] = __builtin_amdgcn_mfma_f32_16x16x32_bf16(ay[m], bi, gi[m][g], 0, 0, 0);
                gh[m][g] = __builtin_amdgcn_mfma_f32_16x16x32_bf16(ah[m], bh, gh[m][g], 0, 0, 0);
            }
        }
    }

    // --- epilogue: GRU gates (f32) + scatter store ---
    const int* idxp = (const int*)(sm + L_IDX);
    #pragma unroll
    for (int m = 0; m < 2; ++m) {
        #pragma unroll
        for (int r = 0; r < 4; ++r) {
            int node = (((wrh << 1) + m) << 4) + (lk << 2) + r;
            if (node < mcnt) {
                int gidx = idxp[node];
                float rv = gi[m][0][r] + bir + gh[m][0][r] + bhr;
                float rg = 1.f / (1.f + __expf(-rv));
                float zv = gi[m][1][r] + biz + gh[m][1][r] + bhz;
                float zg = 1.f / (1.f + __expf(-zv));
                float ng = tanhf(gi[m][2][r] + bnn + rg * (gh[m][2][r] + bhn));
                float hold = *(const float*)(sm + L_HF + (node << 8) + (col << 2));
                out[(size_t)gidx * OUTF + col] = (1.f - zg) * ng + zg * hold;
            }
        }
    }
}

extern "C" void kernel_launch(void* const* d_in, const int* in_sizes, int n_in,
                              void* d_out, int out_size, void* d_ws, size_t ws_size,
                              hipStream_t stream) {
    const float* agg   = (const float*)d_in[0];
    const float* h     = (const float*)d_in[1];
    const int*   ntype = (const int*)d_in[2];
    const float* W_att = (const float*)d_in[3];
    const float* b_att = (const float*)d_in[4];
    const float* W_in  = (const float*)d_in[5];
    const float* W_hid = (const float*)d_in[6];
    const float* b_in  = (const float*)d_in[7];
    const float* b_hid = (const float*)d_in[8];
    float* out = (float*)d_out;

    char* ws = (char*)d_ws;
    int* cursors = (int*)(ws + WS_CURS);
    int* perm = (int*)(ws + WS_PERM);
    unsigned short* waT = (unsigned short*)(ws + WS_WAT);
    unsigned short* wiT = (unsigned short*)(ws + WS_WIT);
    unsigned short* whT = (unsigned short*)(ws + WS_WHT);
    int* counts = (int*)(ws + WS_CNT);

    prep_and_count<<<112, 256, 0, stream>>>(W_att, W_in, W_hid, ntype, counts, waT, wiT, whT);
    scatter_pass<<<SCAT_BLKS, 256, 0, stream>>>(ntype, counts, cursors, perm);
    fused_rgnn<<<MAXBLK, 512, 0, stream>>>(agg, h, cursors, perm,
        waT, wiT, whT, b_att, b_in, b_hid, out);
}